// Round 5
// baseline (489.502 us; speedup 1.0000x reference)
//
#include <hip/hip_runtime.h>
#include <hip/hip_bf16.h>
#include <math.h>

#define B_ 64
#define T_ 2048
#define D_ 512
#define A_ 128
#define TPB 128                  // tiles per batch (T_/16)
#define NTILE (B_ * TPB)         // 8192 wave-tiles of 16 tokens

typedef __bf16 bf16x8 __attribute__((ext_vector_type(8)));
typedef float  f32x4  __attribute__((ext_vector_type(4)));

// ---------------- Kernel 0: W1 [512][128] fp32 -> W1T [128][512] bf16 ----------------
__global__ __launch_bounds__(256) void prep_kernel(
    const float* __restrict__ W1, __hip_bfloat16* __restrict__ W1T)
{
    int idx = blockIdx.x * 256 + threadIdx.x;   // 64K elements
    int k = idx >> 7;
    int n = idx & 127;
    W1T[n * D_ + k] = __float2bfloat16(W1[idx]);
}

__device__ inline bf16x8 cvt8(f32x4 a, f32x4 b) {
    bf16x8 r;
    r[0] = (__bf16)a[0]; r[1] = (__bf16)a[1]; r[2] = (__bf16)a[2]; r[3] = (__bf16)a[3];
    r[4] = (__bf16)b[0]; r[5] = (__bf16)b[1]; r[6] = (__bf16)b[2]; r[7] = (__bf16)b[3];
    return r;
}

__device__ inline float fast_tanh(float v) {
    v = fminf(fmaxf(v, -15.f), 15.f);
    float e = __expf(2.f * v);
    return (e - 1.f) / (e + 1.f);
}

// ---------------- Kernel 1: fused scores + unnormalized exp-pooling ----------------
// One wave per block, one 16-token tile per wave. x tile staged to LDS by async DMA.
// LDS layout: piece(c,g,ks,half) = x[tok0+c][ks*32+g*8+half*4 ..+4)
//   at byte offset (ks*2+half)*1024 + (g*16 + (c^ks))*16.
//   - DMA instr (ks,half): lane L (g=L>>4) loads c=(L&15)^ks -> lands at unit L.  (coalesced 128B rows)
//   - B-frag read (col,kgrp,ks): unit kgrp*16+(col^ks)      -> conflict-free.
//   - Pool read (lane: ksl=L&15,g=L>>4; token t): unit g*16+(t^ksl) in block ksl -> conflict-free.
__global__ __launch_bounds__(64) void fused_kernel(
    const float* __restrict__ x, const __hip_bfloat16* __restrict__ W1T_,
    const float* __restrict__ b1, const float* __restrict__ W2,
    const float* __restrict__ b2,
    float* __restrict__ pmu, float* __restrict__ pm2, float* __restrict__ pz)
{
    __shared__ float xs[16 * 512];       // 32 KB
    const __bf16* W1T = (const __bf16*)W1T_;
    const int lane = threadIdx.x;        // 64-thread block = 1 wave
    const int col  = lane & 15;
    const int kgrp = lane >> 4;

    const int  tile    = blockIdx.x;          // 0..8191
    const long tokbase = (long)tile * 16;

    // ---- async DMA: 32 x global_load_lds dwordx4 (32 KB in flight) ----
    for (int ks = 0; ks < 16; ks++) {
        const float* gp = x + (tokbase + (long)(col ^ ks)) * D_ + ks * 32 + kgrp * 8;
        float* lp = xs + ks * 512;            // block (ks, half=0) at float idx ks*512
        __builtin_amdgcn_global_load_lds(
            (__attribute__((address_space(1))) const void*)gp,
            (__attribute__((address_space(3))) void*)lp, 16, 0, 0);
        __builtin_amdgcn_global_load_lds(
            (__attribute__((address_space(1))) const void*)(gp + 4),
            (__attribute__((address_space(3))) void*)(lp + 256), 16, 0, 0);
    }
    __syncthreads();   // forces vmcnt(0) drain; single-wave barrier is cheap

    // ---- phase 1: scores via MFMA (A = W1T from L2, B = x tile from LDS) ----
    f32x4 acc[8];
#pragma unroll
    for (int mt = 0; mt < 8; mt++) acc[mt] = (f32x4){0.f, 0.f, 0.f, 0.f};

    const __bf16* wp = W1T + (long)col * D_;

#pragma unroll 4
    for (int ks = 0; ks < 16; ks++) {
        const int uoff = ks * 512 + (kgrp * 16 + (col ^ ks)) * 4;   // float index
        f32x4 a0 = *(const f32x4*)&xs[uoff];
        f32x4 a1 = *(const f32x4*)&xs[uoff + 256];
        bf16x8 bf = cvt8(a0, a1);
#pragma unroll
        for (int mt = 0; mt < 8; mt++) {
            bf16x8 af = *(const bf16x8*)(wp + (long)mt * 16 * D_ + ks * 32 + kgrp * 8);
            acc[mt] = __builtin_amdgcn_mfma_f32_16x16x32_bf16(af, bf, acc[mt], 0, 0, 0);
        }
    }

    // epilogue: n = mt*16 + kgrp*4 + r ; token = tokbase + col
    float p = 0.f;
#pragma unroll
    for (int mt = 0; mt < 8; mt++) {
#pragma unroll
        for (int r = 0; r < 4; r++) {
            int n = mt * 16 + kgrp * 4 + r;
            p += fast_tanh(acc[mt][r] + b1[n]) * W2[n];
        }
    }
    p += __shfl_xor(p, 16, 64);
    p += __shfl_xor(p, 32, 64);          // all lanes now hold score(token=col)

    const float e = __expf(p + b2[0]);   // |s| <= 11.4: safe unnormalized exp

    // ---- phase 2: pooling from LDS, d in lanes ----
    // lane (ksl=col, g=kgrp) owns d = ksl*32 + g*8 + {0..7}
    const int ksl = col;
    const int g   = kgrp;
    f32x4 mu0 = {0.f,0.f,0.f,0.f}, mu1 = {0.f,0.f,0.f,0.f};
    f32x4 m20 = {0.f,0.f,0.f,0.f}, m21 = {0.f,0.f,0.f,0.f};

#pragma unroll 4
    for (int t = 0; t < 16; t++) {
        float et = __shfl(e, t, 64);
        const int ubase = ksl * 512 + (g * 16 + (t ^ ksl)) * 4;
        f32x4 v0 = *(const f32x4*)&xs[ubase];
        f32x4 v1 = *(const f32x4*)&xs[ubase + 256];
        f32x4 w0 = et * v0;
        f32x4 w1 = et * v1;
        mu0 += w0;  mu1 += w1;
        m20 += w0 * v0;  m21 += w1 * v1;
    }

    const long obase = (long)tile * D_ + ksl * 32 + g * 8;
    *(f32x4*)&pmu[obase]     = mu0;
    *(f32x4*)&pmu[obase + 4] = mu1;
    *(f32x4*)&pm2[obase]     = m20;
    *(f32x4*)&pm2[obase + 4] = m21;

    float z = e;
    z += __shfl_xor(z, 1, 64);
    z += __shfl_xor(z, 2, 64);
    z += __shfl_xor(z, 4, 64);
    z += __shfl_xor(z, 8, 64);           // sum over 16 tokens
    if (lane == 0) pz[tile] = z;
}

// ---------------- Kernel 2: finalize — reduce 128 tile-partials per batch ----------------
// grid = 64 batches x 8 d-chunks of 64.
__global__ __launch_bounds__(256) void finalize_kernel(
    const float* __restrict__ pmu, const float* __restrict__ pm2,
    const float* __restrict__ pz, float* __restrict__ out)
{
    const int bid = blockIdx.x;
    const int b   = bid >> 3;
    const int dc  = (bid & 7) << 6;
    const int tid = threadIdx.x;
    const int tg  = tid >> 6;       // 0..3 tile group
    const int dl  = tid & 63;
    const int d   = dc + dl;

    // Z reduction (all 8 blocks of a batch redundantly compute it — cheap)
    __shared__ float zsh[2];
    float z = (tid < TPB) ? pz[b * TPB + tid] : 0.f;
#pragma unroll
    for (int off = 1; off < 64; off <<= 1) z += __shfl_xor(z, off, 64);
    if (tid < TPB && (tid & 63) == 0) zsh[tid >> 6] = z;

    float mu = 0.f, m2 = 0.f;
    for (int c = tg; c < TPB; c += 4) {
        mu += pmu[((long)b * TPB + c) * D_ + d];
        m2 += pm2[((long)b * TPB + c) * D_ + d];
    }
    __shared__ float smu[4][64];
    __shared__ float sm2[4][64];
    smu[tg][dl] = mu;
    sm2[tg][dl] = m2;
    __syncthreads();

    if (tid < 64) {
        const float invz = 1.0f / (zsh[0] + zsh[1]);
        float M = (smu[0][tid] + smu[1][tid]) + (smu[2][tid] + smu[3][tid]);
        float S = (sm2[0][tid] + sm2[1][tid]) + (sm2[2][tid] + sm2[3][tid]);
        M *= invz;
        S *= invz;
        out[(long)b * (2 * D_) + dc + tid] = M;
        out[(long)b * (2 * D_) + D_ + dc + tid] = sqrtf(fmaxf(S - M * M, 0.f) + 1e-6f);
    }
}

extern "C" void kernel_launch(void* const* d_in, const int* in_sizes, int n_in,
                              void* d_out, int out_size, void* d_ws, size_t ws_size,
                              hipStream_t stream) {
    const float* x  = (const float*)d_in[0];
    const float* W1 = (const float*)d_in[1];
    const float* b1 = (const float*)d_in[2];
    const float* W2 = (const float*)d_in[3];
    const float* b2 = (const float*)d_in[4];
    float* out = (float*)d_out;

    float* ws = (float*)d_ws;
    float* pmu = ws;                                       // NTILE*512 f (16 MB)
    float* pm2 = pmu + (long)NTILE * D_;                   // NTILE*512 f (16 MB)
    float* pz  = pm2 + (long)NTILE * D_;                   // NTILE f
    __hip_bfloat16* W1T = (__hip_bfloat16*)(pz + NTILE);   // 65536 bf16

    prep_kernel<<<256, 256, 0, stream>>>(W1, W1T);
    fused_kernel<<<NTILE, 64, 0, stream>>>(x, W1T, b1, W2, b2, pmu, pm2, pz);
    finalize_kernel<<<B_ * 8, 256, 0, stream>>>(pmu, pm2, pz, out);
}

// Round 6
// 488.445 us; speedup vs baseline: 1.0022x; 1.0022x over previous
//
#include <hip/hip_runtime.h>
#include <hip/hip_bf16.h>
#include <math.h>

#define B_ 64
#define T_ 2048
#define D_ 512
#define A_ 128
#define CH 128                   // tokens per pool chunk
#define NCH (T_ / CH)            // 16 chunks per batch

typedef __bf16 bf16x8 __attribute__((ext_vector_type(8)));
typedef float  f32x4  __attribute__((ext_vector_type(4)));

// ---------------- Kernel 0: W1 [512][128] fp32 -> W1T [128][512] bf16 ----------------
__global__ __launch_bounds__(256) void prep_kernel(
    const float* __restrict__ W1, __hip_bfloat16* __restrict__ W1T)
{
    int idx = blockIdx.x * 256 + threadIdx.x;   // 64K elements
    int k = idx >> 7;
    int n = idx & 127;
    W1T[n * D_ + k] = __float2bfloat16(W1[idx]);
}

__device__ inline bf16x8 cvt8(float4 a, float4 b) {
    bf16x8 r;
    r[0] = (__bf16)a.x; r[1] = (__bf16)a.y; r[2] = (__bf16)a.z; r[3] = (__bf16)a.w;
    r[4] = (__bf16)b.x; r[5] = (__bf16)b.y; r[6] = (__bf16)b.z; r[7] = (__bf16)b.w;
    return r;
}

__device__ inline float fast_tanh(float v) {
    v = fminf(fmaxf(v, -15.f), 15.f);
    float e = __expf(2.f * v);
    return (e - 1.f) / (e + 1.f);
}

// ---------------- Kernel 1: scores -> unnormalized exp weights ----------------
// 256 thr = 4 waves, 64 tokens/wave (256 tok/block). Direct global loads (R2-proven),
// A = W1T rows (L2-hot), B = x rows cvt to bf16. No barriers in K-loop.
__global__ __launch_bounds__(256) void scores_kernel(
    const float* __restrict__ x, const __hip_bfloat16* __restrict__ W1T_,
    const float* __restrict__ b1, const float* __restrict__ W2,
    const float* __restrict__ b2, float* __restrict__ ew)
{
    const __bf16* W1T = (const __bf16*)W1T_;
    const int tid  = threadIdx.x;
    const int wave = tid >> 6;
    const int lane = tid & 63;
    const int col  = lane & 15;
    const int kgrp = lane >> 4;

    const long tokbase = (long)blockIdx.x * 256 + wave * 64;

    f32x4 acc[8][4];
#pragma unroll
    for (int mt = 0; mt < 8; mt++)
#pragma unroll
        for (int tt = 0; tt < 4; tt++)
            acc[mt][tt] = (f32x4){0.f, 0.f, 0.f, 0.f};

    const float*  xp = x + (tokbase + col) * D_;
    const __bf16* wp = W1T + (long)col * D_;

#pragma unroll 2
    for (int ks = 0; ks < 16; ks++) {
        const int klane = ks * 32 + kgrp * 8;
        bf16x8 bf[4];
#pragma unroll
        for (int tt = 0; tt < 4; tt++) {
            float4 a0 = *(const float4*)(xp + (long)tt * 16 * D_ + klane);
            float4 a1 = *(const float4*)(xp + (long)tt * 16 * D_ + klane + 4);
            bf[tt] = cvt8(a0, a1);
        }
#pragma unroll
        for (int mt = 0; mt < 8; mt++) {
            bf16x8 af = *(const bf16x8*)(wp + (long)mt * 16 * D_ + klane);
#pragma unroll
            for (int tt = 0; tt < 4; tt++)
                acc[mt][tt] = __builtin_amdgcn_mfma_f32_16x16x32_bf16(af, bf[tt], acc[mt][tt], 0, 0, 0);
        }
    }

    // epilogue: n = mt*16 + kgrp*4 + r ; token = tokbase + tt*16 + col
    float p[4] = {0.f, 0.f, 0.f, 0.f};
#pragma unroll
    for (int mt = 0; mt < 8; mt++) {
#pragma unroll
        for (int r = 0; r < 4; r++) {
            int n = mt * 16 + kgrp * 4 + r;
            float bb = b1[n];
            float ww = W2[n];
#pragma unroll
            for (int tt = 0; tt < 4; tt++)
                p[tt] += fast_tanh(acc[mt][tt][r] + bb) * ww;
        }
    }
#pragma unroll
    for (int tt = 0; tt < 4; tt++) {
        p[tt] += __shfl_xor(p[tt], 16, 64);
        p[tt] += __shfl_xor(p[tt], 32, 64);
    }
    if (lane < 16) {
        float bias = b2[0];
#pragma unroll
        for (int tt = 0; tt < 4; tt++)
            ew[tokbase + tt * 16 + col] = __expf(p[tt] + bias);  // |s|<=11.4: fp32-safe
    }
}

// ---------------- Kernel 2: pooling partials over 128-token chunks ----------------
// grid: 64 b x 16 chunks. 256 threads: 2 full rows (512 f) per iter. Also partial Z.
__global__ __launch_bounds__(256) void pool_partial_kernel(
    const float* __restrict__ x, const float* __restrict__ ew,
    float* __restrict__ pmu, float* __restrict__ pm2, float* __restrict__ pz)
{
    const int blk = blockIdx.x;
    const int b = blk >> 4;
    const int t0 = (blk & 15) * CH;
    const int tid = threadIdx.x;
    const int half = tid >> 7;
    const int dq = tid & 127;

    const float* wb = ew + (long)b * T_ + t0;
    const float* xb = x + ((long)b * T_ + t0) * D_ + dq * 4;

    float4 mu = {0.f, 0.f, 0.f, 0.f};
    float4 m2 = {0.f, 0.f, 0.f, 0.f};

#pragma unroll 4
    for (int t = half; t < CH; t += 2) {
        float wt = wb[t];
        float4 xv = *(const float4*)(xb + (long)t * D_);
        mu.x = fmaf(wt, xv.x, mu.x);
        mu.y = fmaf(wt, xv.y, mu.y);
        mu.z = fmaf(wt, xv.z, mu.z);
        mu.w = fmaf(wt, xv.w, mu.w);
        m2.x = fmaf(wt * xv.x, xv.x, m2.x);
        m2.y = fmaf(wt * xv.y, xv.y, m2.y);
        m2.z = fmaf(wt * xv.z, xv.z, m2.z);
        m2.w = fmaf(wt * xv.w, xv.w, m2.w);
    }

    __shared__ float4 smu[256];
    __shared__ float4 sm2[256];
    smu[tid] = mu;
    sm2[tid] = m2;
    __syncthreads();

    if (tid < 128) {
        float4 a = smu[tid], c = smu[tid + 128];
        float4 e = sm2[tid], f = sm2[tid + 128];
        a.x += c.x; a.y += c.y; a.z += c.z; a.w += c.w;
        e.x += f.x; e.y += f.y; e.z += f.z; e.w += f.w;
        *(float4*)(pmu + (long)blk * D_ + dq * 4) = a;
        *(float4*)(pm2 + (long)blk * D_ + dq * 4) = e;
    } else if (tid >= 192) {
        // lanes 192..255 (one wave): partial Z for this chunk
        int l = tid - 192;
        float z = wb[l] + wb[l + 64];
#pragma unroll
        for (int off = 1; off < 64; off <<= 1) z += __shfl_xor(z, off, 64);
        if (l == 0) pz[blk] = z;
    }
}

// ---------------- Kernel 3: finalize — reduce 16 chunk-partials, normalize ----------------
__global__ __launch_bounds__(256) void finalize_kernel(
    const float* __restrict__ pmu, const float* __restrict__ pm2,
    const float* __restrict__ pz, float* __restrict__ out)
{
    const int b = blockIdx.x;
    const int tid = threadIdx.x;

    __shared__ float zsh;
    if (tid < 64) {
        float z = (tid < NCH) ? pz[b * NCH + tid] : 0.f;
#pragma unroll
        for (int off = 1; off < 16; off <<= 1) z += __shfl_xor(z, off, 64);
        if (tid == 0) zsh = z;
    }
    __syncthreads();
    const float invz = 1.0f / zsh;

#pragma unroll
    for (int i = 0; i < 2; i++) {
        int d = tid + i * 256;
        float mu = 0.f, m2 = 0.f;
#pragma unroll
        for (int c = 0; c < NCH; c++) {
            mu += pmu[((long)b * NCH + c) * D_ + d];
            m2 += pm2[((long)b * NCH + c) * D_ + d];
        }
        mu *= invz;
        m2 *= invz;
        out[(long)b * (2 * D_) + d] = mu;
        out[(long)b * (2 * D_) + D_ + d] = sqrtf(fmaxf(m2 - mu * mu, 0.f) + 1e-6f);
    }
}

extern "C" void kernel_launch(void* const* d_in, const int* in_sizes, int n_in,
                              void* d_out, int out_size, void* d_ws, size_t ws_size,
                              hipStream_t stream) {
    const float* x  = (const float*)d_in[0];
    const float* W1 = (const float*)d_in[1];
    const float* b1 = (const float*)d_in[2];
    const float* W2 = (const float*)d_in[3];
    const float* b2 = (const float*)d_in[4];
    float* out = (float*)d_out;

    const int nblk = B_ * NCH;                             // 1024 pool chunks
    float* ws  = (float*)d_ws;
    float* ew  = ws;                                       // B*T f
    float* pmu = ew + (long)B_ * T_;                       // nblk*512 f
    float* pm2 = pmu + (long)nblk * D_;                    // nblk*512 f
    float* pz  = pm2 + (long)nblk * D_;                    // nblk f
    __hip_bfloat16* W1T = (__hip_bfloat16*)(pz + nblk);    // 65536 bf16

    prep_kernel<<<256, 256, 0, stream>>>(W1, W1T);
    scores_kernel<<<(B_ * T_) / 256, 256, 0, stream>>>(x, W1T, b1, W2, b2, ew);
    pool_partial_kernel<<<nblk, 256, 0, stream>>>(x, ew, pmu, pm2, pz);
    finalize_kernel<<<B_, 256, 0, stream>>>(pmu, pm2, pz, out);
}